// Round 13
// baseline (302.927 us; speedup 1.0000x reference)
//
#include <hip/hip_runtime.h>
#include <hip/hip_bf16.h>

#define MM 127
#define CHUNK_U16 4096        // per (matrix, k-chunk): 512 slots * 8 u16 = 8 KB
#define MAT_U16   16384       // 4 chunks per matrix = 32 KB
#define ARR_U16   1048576     // 64 matrices = 2 MB per array (X, Y)
#define QS_STRIDE 136         // per-lane stream stride (dwords); uniform banks
#define QS_DWORDS (64 * QS_STRIDE)   // 8704 dwords = 34,816 B
#define NBIN 64

typedef __attribute__((ext_vector_type(8))) short short8;
typedef __attribute__((ext_vector_type(4))) float floatx4;
typedef __attribute__((ext_vector_type(2))) float f32x2;

__device__ __forceinline__ unsigned short f2bf_rne(float x) {
  unsigned int u = __float_as_uint(x);
  u += 0x7FFFu + ((u >> 16) & 1u);
  return (unsigned short)(u >> 16);
}

__device__ __forceinline__ void gload_lds16(const void* g, void* l) {
  __builtin_amdgcn_global_load_lds(
      (const __attribute__((address_space(1))) unsigned int*)g,
      (__attribute__((address_space(3))) unsigned int*)l, 16, 0, 0);
}

// wave_shr:1 via DPP: lane l gets lane l-1's value; lane 0 gets 0 (bound_ctrl)
__device__ __forceinline__ float wave_shr1(float x) {
  return __int_as_float(__builtin_amdgcn_update_dpp(
      0, __float_as_int(x), 0x138, 0xf, 0xf, true));
}

// ---- prep: increments -> RNE bf16, frag-image layout (R9-verified), 1024 blocks ----
__global__ __launch_bounds__(256) void prep_kernel(
    const float* __restrict__ X, const float* __restrict__ Y,
    unsigned short* __restrict__ base, float* __restrict__ bins,
    unsigned int* __restrict__ counter)
{
  if (blockIdx.x == 0) {
    if (threadIdx.x < NBIN) bins[threadIdx.x * 32] = 0.f;
    if (threadIdx.x == 64) counter[0] = 0u;
  }
  const int bid = blockIdx.x;          // 0..1023
  const int isY = bid >> 9;
  const int m = (bid >> 3) & 63;
  const int c = (bid >> 1) & 3;
  const int h = bid & 1;
  const float* src = (isY ? Y : X) + m * 128 * 128;
  unsigned short* dst = base + isY * ARR_U16 + m * MAT_U16 + c * CHUNK_U16;

  const int s = h * 256 + threadIdx.x;   // 0..511
  const int r = s >> 2;
  const int g = (s & 3) ^ (r & 3);
  uint4 hv = make_uint4(0, 0, 0, 0);
  if (r < MM) {
    const float* p = src + r * 128 + c * 32 + g * 8;
    float4 u0 = *reinterpret_cast<const float4*>(p);
    float4 u1 = *reinterpret_cast<const float4*>(p + 4);
    float4 v0 = *reinterpret_cast<const float4*>(p + 128);
    float4 v1 = *reinterpret_cast<const float4*>(p + 132);
    float d[8] = {v0.x - u0.x, v0.y - u0.y, v0.z - u0.z, v0.w - u0.w,
                  v1.x - u1.x, v1.y - u1.y, v1.z - u1.z, v1.w - u1.w};
    unsigned int hw[4];
#pragma unroll
    for (int e = 0; e < 4; ++e) {
      float2 rr; rr.x = d[2 * e]; rr.y = d[2 * e + 1];
      __hip_bfloat162 hp = __float22bfloat162_rn(rr);
      unsigned int hu; __builtin_memcpy(&hu, &hp, 4);
      hw[e] = hu;
    }
    hv = make_uint4(hw[0], hw[1], hw[2], hw[3]);
  }
  *reinterpret_cast<uint4*>(dst + s * 8) = hv;
}

__global__ __launch_bounds__(256, 4) void sig_pair_kernel(
    const unsigned short* __restrict__ base, float* __restrict__ bins,
    unsigned int* __restrict__ counter, unsigned int* __restrict__ out)
{
  // LDS 34,816 B (4 blocks/CU). GEMM: dbuf staging (R10/R11-verified).
  // PDE: lane-skewed stream qS[64][136] dwords (R11-verified layout).
  __shared__ unsigned int smw[QS_DWORDS];
  unsigned short* const sm = reinterpret_cast<unsigned short*>(smw);
  const int tid = threadIdx.x;
  const int bid = blockIdx.x;

  // ---- decode block -> (gram type, a, b, weight) ----
  float w;
  int a, b, srcA, srcB;
  if (bid < 4160) {
    int p = bid;
    srcA = 0;
    if (p >= 2080) { p -= 2080; srcA = 1; }
    srcB = srcA;
    int ia = (int)((sqrtf(8.0f * (float)p + 1.0f) - 1.0f) * 0.5f);
    while ((ia + 1) * (ia + 2) / 2 <= p) ia++;
    while (ia * (ia + 1) / 2 > p) ia--;
    int ib = p - ia * (ia + 1) / 2;
    a = ia; b = ib;
    w = (a == b ? 1.0f : 2.0f) / 4096.0f;
  } else {
    int p = bid - 4160;
    a = p >> 6; b = p & 63;
    srcA = 0; srcB = 1;
    w = -2.0f / 4096.0f;
  }
  const unsigned short* Am = base + srcA * ARR_U16 + a * MAT_U16;
  const unsigned short* Bm = base + srcB * ARR_U16 + b * MAT_U16;

  const int wid = tid >> 6, lane = tid & 63;
  const int row0 = (wid >> 1) * 64, col0 = (wid & 1) * 64;
  const int lrow = lane & 15, quad = lane >> 4;

  const unsigned short* gp = ((wid < 2) ? Am : Bm) + (wid & 1) * 2048 + lane * 8;
  const unsigned int dq = wid * 2048;

  floatx4 acc4[4][4];
#pragma unroll
  for (int tr = 0; tr < 4; ++tr)
#pragma unroll
    for (int tc = 0; tc < 4; ++tc) acc4[tr][tc] = (floatx4){0.f, 0.f, 0.f, 0.f};

#pragma unroll
  for (int s = 0; s < 4; ++s)
    gload_lds16(gp + s * 512, &sm[dq + s * 512]);

  for (int c = 0; c < 4; ++c) {
    __syncthreads();
    if (c < 3) {
      const unsigned short* g = gp + (c + 1) * CHUNK_U16;
      const unsigned int db_ = ((c + 1) & 1) * 8192 + dq;
#pragma unroll
      for (int s = 0; s < 4; ++s)
        gload_lds16(g + s * 512, &sm[db_ + s * 512]);
    }
    const unsigned int bb = (c & 1) * 8192;
    short8 bh[4];
#pragma unroll
    for (int tc = 0; tc < 4; ++tc) {
      int r = col0 + tc * 16 + lrow;
      int off = r * 32 + ((quad ^ (r & 3)) * 8);
      bh[tc] = *reinterpret_cast<const short8*>(&sm[bb + 4096 + off]);
    }
#pragma unroll
    for (int tr = 0; tr < 4; ++tr) {
      int r = row0 + tr * 16 + lrow;
      int off = r * 32 + ((quad ^ (r & 3)) * 8);
      short8 ah = *reinterpret_cast<const short8*>(&sm[bb + off]);
#pragma unroll
      for (int tc = 0; tc < 4; ++tc)
        acc4[tr][tc] = __builtin_amdgcn_mfma_f32_16x16x32_bf16(ah, bh[tc], acc4[tr][tc], 0, 0, 0);
    }
  }
  __syncthreads();

  // ---- zero-fill the stream image (zeros = m-1 == -1 borders) ----
  for (int i = tid; i < QS_DWORDS; i += 256) smw[i] = 0u;
  __syncthreads();

  // ---- epilogue: M (bf16) into consumer (lane, phys) slots (R11-verified) ----
#pragma unroll
  for (int tr = 0; tr < 4; ++tr) {
#pragma unroll
    for (int tc = 0; tc < 4; ++tc) {
      int jm = col0 + tc * 16 + lrow;
#pragma unroll
      for (int e = 0; e < 4; ++e) {
        int im = row0 + tr * 16 + quad * 4 + e;
        if (im < MM && jm < MM) {
          int lt = (jm + 1) >> 1;
          int phys = im + jm + 5 - 4 * (lt >> 1) - 4 * (lt & 1);
          int half = (jm & 1) ? 0 : 1;
          sm[(lt * QS_STRIDE + phys) * 2 + half] = f2bf_rne(acc4[tr][tc][e]);
        }
      }
    }
  }
  __syncthreads();

  // ---- Phase 2: streamed PDE, packed-f32 pair math, on wave (bid & 3) ----
  // cur = pk_fma(np, m-1, cur) + nc;  nc = (dpp(cur.y), cur.x);  np = nc.
  // lane 0: nc.x = 0 (DPP bound_ctrl) and np.x init 0 -> col 0 stays 1.0.
  if (wid == (bid & 3)) {
    const int l = lane;
    const int shift = 4 * (l >> 1) + 4 * (l & 1) - 4;
    const unsigned int lbase = l * QS_STRIDE;

    auto loadg = [&](int g) -> uint4 {
      int pb = 4 * g - shift;
      pb = pb < 0 ? 132 : (pb > 128 ? 128 : pb);   // pre-band -> zero pad
      return *reinterpret_cast<const uint4*>(&smw[lbase + pb]);
    };

    f32x2 cur; cur.x = 1.f; cur.y = 1.f;
    f32x2 np;  np.x = (l == 0) ? 0.f : 1.f; np.y = 1.f;
    const f32x2 mone = {-1.f, -1.f};
    uint4 P0 = loadg(0), P1 = loadg(1);

    for (int g = 0; g < 63; ++g) {       // groups cover t = 0..251
      const uint4 curg = P0;
      P0 = P1;
      if (g < 62) P1 = loadg(g + 2);
      unsigned int uu[4] = {curg.x, curg.y, curg.z, curg.w};
#pragma unroll
      for (int e = 0; e < 4; ++e) {
        unsigned int u = uu[e];
        f32x2 m1;
        m1.x = __uint_as_float(u << 16);
        m1.y = __uint_as_float(u & 0xFFFF0000u);
        m1 = m1 + mone;                      // v_pk_add_f32
        f32x2 nc;
        nc.x = wave_shr1(cur.y);
        nc.y = cur.x;
        cur = __builtin_elementwise_fma(np, m1, cur) + nc;  // pk_fma + pk_add
        np = nc;
      }
    }
    // tail: t = 252, 253 from group 63 (already in P0)
    {
      unsigned int uu[2] = {P0.x, P0.y};
#pragma unroll
      for (int e = 0; e < 2; ++e) {
        unsigned int u = uu[e];
        f32x2 m1;
        m1.x = __uint_as_float(u << 16);
        m1.y = __uint_as_float(u & 0xFFFF0000u);
        m1 = m1 + mone;
        f32x2 nc;
        nc.x = wave_shr1(cur.y);
        nc.y = cur.x;
        cur = __builtin_elementwise_fma(np, m1, cur) + nc;
        np = nc;
      }
    }
    if (l == 63) {
      atomicAdd(&bins[(bid & 63) * 32], w * cur.y);   // col 127 = odd col lane 63
      __threadfence();
      unsigned int t = atomicAdd(counter, 1u);
      if (t == 8255u) {                                // last block: finalize
        __threadfence();
        float v = 0.f;
        for (int i = 0; i < NBIN; ++i) v += atomicAdd(&bins[i * 32], 0.f);
        __hip_bfloat16 bv = __float2bfloat16(v);
        unsigned short us;
        __builtin_memcpy(&us, &bv, sizeof(us));
        out[0] = ((unsigned int)us << 16) | (unsigned int)us;
      }
    }
  }
}

extern "C" void kernel_launch(void* const* d_in, const int* in_sizes, int n_in,
                              void* d_out, int out_size, void* d_ws, size_t ws_size,
                              hipStream_t stream) {
  const float* X = (const float*)d_in[0];
  const float* Y = (const float*)d_in[1];
  float* bins = (float*)d_ws;                                      // 64 bins, 128 B apart
  unsigned int* counter = (unsigned int*)((char*)d_ws + 8192);
  unsigned short* base = (unsigned short*)((char*)d_ws + 16384);   // 4 MB arrays

  prep_kernel<<<1024, 256, 0, stream>>>(X, Y, base, bins, counter);
  sig_pair_kernel<<<8256, 256, 0, stream>>>(base, bins, counter,
                                            (unsigned int*)d_out);
}